// Round 1
// baseline (625.378 us; speedup 1.0000x reference)
//
#include <hip/hip_runtime.h>
#include <math.h>

#define SEQ 1024
#define NH 12
#define CC 768

using short8 = __attribute__((ext_vector_type(8))) short;
using bf16x8 = __attribute__((ext_vector_type(8))) __bf16;
using f32x4  = __attribute__((ext_vector_type(4))) float;

__device__ __forceinline__ unsigned short f2bf(float f){
  unsigned u = __builtin_bit_cast(unsigned, f);
  u += 0x7FFF + ((u >> 16) & 1);
  return (unsigned short)(u >> 16);
}

__device__ __forceinline__ void gload16(const void* g, void* l){
  __builtin_amdgcn_global_load_lds((const __attribute__((address_space(1))) unsigned int*)g,
                                   (__attribute__((address_space(3))) unsigned int*)l, 16, 0, 0);
}
__device__ __forceinline__ bf16x8 lds_frag(const unsigned short* p){
  return __builtin_bit_cast(bf16x8, *(const short8*)p);
}
__device__ __forceinline__ bf16x8 gld_frag(const unsigned short* p){
  return __builtin_bit_cast(bf16x8, *(const short8*)p);
}

// ---------------- weight transpose + bf16 convert: W(K,N) f32 -> Wt(N,K) bf16
__global__ __launch_bounds__(256) void wtrans(const float* __restrict__ W,
                                              unsigned short* __restrict__ Wt,
                                              int K, int N){
  __shared__ float tile[32][33];
  int tx = threadIdx.x & 31, ty = threadIdx.x >> 5;
  int n0 = blockIdx.x * 32, k0 = blockIdx.y * 32;
#pragma unroll
  for (int j = 0; j < 4; j++)
    tile[ty + j*8][tx] = W[(size_t)(k0 + ty + j*8) * N + n0 + tx];
  __syncthreads();
#pragma unroll
  for (int j = 0; j < 4; j++)
    Wt[(size_t)(n0 + ty + j*8) * K + k0 + tx] = f2bf(tile[tx][ty + j*8]);
}

// ---------------- layernorm fp32 -> bf16, one wave per row of 768
__global__ __launch_bounds__(64) void ln_k(const float* __restrict__ x,
                                           const float* __restrict__ g,
                                           const float* __restrict__ be,
                                           unsigned short* __restrict__ out){
  const int row = blockIdx.x;
  const int lane = threadIdx.x;
  const float* xr = x + (size_t)row * CC;
  float4 v[3];
  float s = 0.f, sq = 0.f;
#pragma unroll
  for (int j = 0; j < 3; j++){
    v[j] = *(const float4*)(xr + lane*4 + j*256);
    s  += v[j].x + v[j].y + v[j].z + v[j].w;
    sq += v[j].x*v[j].x + v[j].y*v[j].y + v[j].z*v[j].z + v[j].w*v[j].w;
  }
#pragma unroll
  for (int d = 1; d < 64; d <<= 1){ s += __shfl_xor(s, d); sq += __shfl_xor(sq, d); }
  float mu = s * (1.0f/CC);
  float var = sq * (1.0f/CC) - mu*mu;
  float rstd = rsqrtf(var + 1e-5f);
  unsigned short* orow = out + (size_t)row * CC;
#pragma unroll
  for (int j = 0; j < 3; j++){
    int cb = lane*4 + j*256;
    float4 gv = *(const float4*)(g + cb);
    float4 bv = *(const float4*)(be + cb);
    ushort4 o;
    o.x = f2bf((v[j].x - mu)*rstd*gv.x + bv.x);
    o.y = f2bf((v[j].y - mu)*rstd*gv.y + bv.y);
    o.z = f2bf((v[j].z - mu)*rstd*gv.z + bv.z);
    o.w = f2bf((v[j].w - mu)*rstd*gv.w + bv.w);
    *(ushort4*)(orow + cb) = o;
  }
}

// ---------------- V^T extraction: qkv(B*N,2304) -> vT(B*H, 64, 1024)
__global__ __launch_bounds__(256) void vextract(const unsigned short* __restrict__ qkv,
                                                unsigned short* __restrict__ vT){
  __shared__ unsigned short tile[32][33];
  int bh = blockIdx.y;
  int b = bh / NH, h = bh % NH;
  int tt = blockIdx.x & 31, dt = blockIdx.x >> 5;
  int tx = threadIdx.x & 31, ty = threadIdx.x >> 5;
#pragma unroll
  for (int j = 0; j < 4; j++)
    tile[ty + j*8][tx] = qkv[(size_t)(b*SEQ + tt*32 + ty + j*8)*2304 + 1536 + h*64 + dt*32 + tx];
  __syncthreads();
#pragma unroll
  for (int j = 0; j < 4; j++)
    vT[((size_t)bh*64 + dt*32 + ty + j*8)*SEQ + tt*32 + tx] = tile[tx][ty + j*8];
}

// ---------------- GEMM: C(M,N) = A(M,K)bf16 * Bt(N,K)bf16^T, fused epilogue
// MODE 0: out bf16 = acc + bias
// MODE 1: out f32  = resid + acc + bias
// MODE 2: out bf16 = gelu_exact(acc + bias)
template<int MODE>
__global__ __launch_bounds__(256, 2) void gemm_bt(const unsigned short* __restrict__ A,
                                                  const unsigned short* __restrict__ Bt,
                                                  const float* __restrict__ bias,
                                                  const float* __restrict__ resid,
                                                  void* __restrict__ outp,
                                                  int M, int N, int K){
  __shared__ __align__(16) unsigned short As[2][128*32];
  __shared__ __align__(16) unsigned short Bs[2][128*32];
  const int t = threadIdx.x;
  const int lane = t & 63;
  const int w = t >> 6;
  const int wr = w >> 1, wc = w & 1;
  const int l15 = lane & 15, lg = lane >> 4;
  const int mtiles = M >> 7;
  const int bm = blockIdx.x % mtiles;
  const int bn = blockIdx.x / mtiles;
  const unsigned short* Abase = A + (size_t)bm * 128 * K;
  const unsigned short* Bbase = Bt + (size_t)bn * 128 * K;

  f32x4 acc[4][4] = {};
  const int nk = K >> 5;
  int buf = 0;

  // prologue stage kt=0
#pragma unroll
  for (int i = 0; i < 2; i++){
    int idx = i*256 + t; int r = idx >> 2; int s = idx & 3; int ss = s ^ ((r >> 1) & 3);
    gload16(Abase + (size_t)r*K + ss*8, &As[0][idx*8]);
  }
#pragma unroll
  for (int i = 0; i < 2; i++){
    int idx = i*256 + t; int r = idx >> 2; int s = idx & 3; int ss = s ^ ((r >> 1) & 3);
    gload16(Bbase + (size_t)r*K + ss*8, &Bs[0][idx*8]);
  }
  __syncthreads();

  for (int kt = 0; kt < nk; ++kt){
    if (kt + 1 < nk){
      const unsigned short* Ak = Abase + (kt + 1) * 32;
      const unsigned short* Bk = Bbase + (kt + 1) * 32;
#pragma unroll
      for (int i = 0; i < 2; i++){
        int idx = i*256 + t; int r = idx >> 2; int s = idx & 3; int ss = s ^ ((r >> 1) & 3);
        gload16(Ak + (size_t)r*K + ss*8, &As[buf^1][idx*8]);
      }
#pragma unroll
      for (int i = 0; i < 2; i++){
        int idx = i*256 + t; int r = idx >> 2; int s = idx & 3; int ss = s ^ ((r >> 1) & 3);
        gload16(Bk + (size_t)r*K + ss*8, &Bs[buf^1][idx*8]);
      }
    }
    bf16x8 af[4], bfr[4];
#pragma unroll
    for (int m = 0; m < 4; m++){
      int rr = wr*64 + m*16 + l15;
      int s = lg ^ ((rr >> 1) & 3);
      af[m] = lds_frag(&As[buf][rr*32 + s*8]);
    }
#pragma unroll
    for (int n = 0; n < 4; n++){
      int rr = wc*64 + n*16 + l15;
      int s = lg ^ ((rr >> 1) & 3);
      bfr[n] = lds_frag(&Bs[buf][rr*32 + s*8]);
    }
#pragma unroll
    for (int m = 0; m < 4; m++)
#pragma unroll
      for (int n = 0; n < 4; n++)
        acc[m][n] = __builtin_amdgcn_mfma_f32_16x16x32_bf16(af[m], bfr[n], acc[m][n], 0, 0, 0);
    __syncthreads();
    buf ^= 1;
  }

  // epilogue
  const int row0 = bm*128 + wr*64 + lg*4;
  const int col0 = bn*128 + wc*64 + l15;
#pragma unroll
  for (int n = 0; n < 4; n++){
    int c = col0 + n*16;
    float bv = bias[c];
#pragma unroll
    for (int m = 0; m < 4; m++){
      int r = row0 + m*16;
#pragma unroll
      for (int i = 0; i < 4; i++){
        size_t idx = (size_t)(r + i) * N + c;
        float v = acc[m][n][i] + bv;
        if constexpr (MODE == 0){
          ((unsigned short*)outp)[idx] = f2bf(v);
        } else if constexpr (MODE == 1){
          ((float*)outp)[idx] = resid[idx] + v;
        } else {
          float gv = 0.5f * v * (1.0f + erff(v * 0.70710678118654752440f));
          ((unsigned short*)outp)[idx] = f2bf(gv);
        }
      }
    }
  }
}

// ---------------- flash attention: 128 q-rows/block, 4 waves x 32 rows, KV tiles of 64
__global__ __launch_bounds__(256, 2) void attn_k(const unsigned short* __restrict__ qkv,
                                                 const unsigned short* __restrict__ vT,
                                                 unsigned short* __restrict__ aout){
  __shared__ __align__(16) unsigned short Ks[2][64*64];
  __shared__ __align__(16) unsigned short Vs[2][64*64];
  __shared__ __align__(16) unsigned short Ps[4][32*64];
  const int t = threadIdx.x, lane = t & 63, w = t >> 6;
  const int l15 = lane & 15, lg = lane >> 4;
  const int qt = blockIdx.x;   // 0..7
  const int bh = blockIdx.y;   // 0..191
  const int b = bh / NH, h = bh % NH;
  const size_t qrow0 = (size_t)b * SEQ + qt*128 + w*32;

  // Q fragments (B-operand of S^T = K*Q^T): lane holds Q[q=l15][d slice]
  bf16x8 qf[2][2];
#pragma unroll
  for (int nf = 0; nf < 2; nf++)
#pragma unroll
    for (int ks = 0; ks < 2; ks++)
      qf[nf][ks] = gld_frag(qkv + (qrow0 + nf*16 + l15)*2304 + h*64 + ks*32 + lg*8);

  f32x4 o[2][4] = {};
  float mold[2] = {-3.0e38f, -3.0e38f};
  float lsum[2] = {0.f, 0.f};

  const unsigned short* Kgl = qkv + (size_t)b * SEQ * 2304 + 768 + h*64;
  const unsigned short* Vgl = vT + (size_t)bh * 64 * SEQ;

  auto stageKV = [&](int bufi, int kt){
#pragma unroll
    for (int i = 0; i < 2; i++){
      int idx = i*256 + t; int r = idx >> 3; int s = idx & 7; int ss = s ^ (r & 7);
      gload16(Kgl + (size_t)(kt*64 + r)*2304 + ss*8, &Ks[bufi][idx*8]);
    }
#pragma unroll
    for (int i = 0; i < 2; i++){
      int idx = i*256 + t; int r = idx >> 3; int s = idx & 7; int ss = s ^ (r & 7);
      gload16(Vgl + (size_t)r*SEQ + kt*64 + ss*8, &Vs[bufi][idx*8]);
    }
  };

  stageKV(0, 0);
  __syncthreads();
  int buf = 0;

  for (int kt = 0; kt < 16; ++kt){
    if (kt + 1 < 16) stageKV(buf ^ 1, kt + 1);

    // S^T(kv,q) = K * Q^T
    f32x4 st[4][2] = {};
#pragma unroll
    for (int ks = 0; ks < 2; ks++){
      bf16x8 kf[4];
#pragma unroll
      for (int mf = 0; mf < 4; mf++){
        int rr = mf*16 + l15;
        int sc = (ks*4 + lg) ^ (rr & 7);
        kf[mf] = lds_frag(&Ks[buf][rr*64 + sc*8]);
      }
#pragma unroll
      for (int mf = 0; mf < 4; mf++)
#pragma unroll
        for (int nf = 0; nf < 2; nf++)
          st[mf][nf] = __builtin_amdgcn_mfma_f32_16x16x32_bf16(kf[mf], qf[nf][ks], st[mf][nf], 0, 0, 0);
    }

    // online softmax over kv (rows of S^T); lane's q-row = nf*16 + l15
    float fsc[2];
#pragma unroll
    for (int nf = 0; nf < 2; nf++){
      float mx = -3.0e38f;
#pragma unroll
      for (int mf = 0; mf < 4; mf++)
#pragma unroll
        for (int i = 0; i < 4; i++){
          float sv = st[mf][nf][i] * 0.125f;
          st[mf][nf][i] = sv;
          mx = fmaxf(mx, sv);
        }
      mx = fmaxf(mx, __shfl_xor(mx, 16));
      mx = fmaxf(mx, __shfl_xor(mx, 32));
      float nm = fmaxf(mold[nf], mx);
      float f = __expf(mold[nf] - nm);
      mold[nf] = nm;
      float rs = 0.f;
#pragma unroll
      for (int mf = 0; mf < 4; mf++)
#pragma unroll
        for (int i = 0; i < 4; i++){
          float p = __expf(st[mf][nf][i] - nm);
          st[mf][nf][i] = p;
          rs += p;
        }
      rs += __shfl_xor(rs, 16);
      rs += __shfl_xor(rs, 32);
      lsum[nf] = lsum[nf]*f + rs;
      fsc[nf] = f;
    }

    // write P to per-wave swizzled LDS tile [32 q][64 kv]
#pragma unroll
    for (int nf = 0; nf < 2; nf++)
#pragma unroll
      for (int mf = 0; mf < 4; mf++)
#pragma unroll
        for (int i = 0; i < 4; i++){
          int rP = nf*16 + l15;
          int col = mf*16 + lg*4 + i;
          Ps[w][rP*64 + (col ^ ((rP & 7) << 3))] = f2bf(st[mf][nf][i]);
        }

    // rescale O by f (broadcast f to O's row layout)
#pragma unroll
    for (int mm = 0; mm < 2; mm++)
#pragma unroll
      for (int i = 0; i < 4; i++){
        float fo = __shfl(fsc[mm], lg*4 + i);
#pragma unroll
        for (int df = 0; df < 4; df++)
          o[mm][df][i] *= fo;
      }

    // PV: O += P * V   (A=P rows q, B=V via V^T tile rows d)
#pragma unroll
    for (int ks = 0; ks < 2; ks++){
      bf16x8 pf[2], vf[4];
#pragma unroll
      for (int mm = 0; mm < 2; mm++){
        int rP = mm*16 + l15;
        int sc = (ks*4 + lg) ^ (rP & 7);
        pf[mm] = lds_frag(&Ps[w][rP*64 + sc*8]);
      }
#pragma unroll
      for (int df = 0; df < 4; df++){
        int rr = df*16 + l15;
        int sc = (ks*4 + lg) ^ (rr & 7);
        vf[df] = lds_frag(&Vs[buf][rr*64 + sc*8]);
      }
#pragma unroll
      for (int mm = 0; mm < 2; mm++)
#pragma unroll
        for (int df = 0; df < 4; df++)
          o[mm][df] = __builtin_amdgcn_mfma_f32_16x16x32_bf16(pf[mm], vf[df], o[mm][df], 0, 0, 0);
    }
    __syncthreads();
    buf ^= 1;
  }

  // epilogue: normalize and store bf16
#pragma unroll
  for (int mm = 0; mm < 2; mm++){
    float li = 1.0f / lsum[mm];
#pragma unroll
    for (int i = 0; i < 4; i++){
      float rl = __shfl(li, lg*4 + i);
      size_t r = qrow0 + mm*16 + lg*4 + i;
#pragma unroll
      for (int df = 0; df < 4; df++)
        aout[r*CC + h*64 + df*16 + l15] = f2bf(o[mm][df][i] * rl);
    }
  }
}

extern "C" void kernel_launch(void* const* d_in, const int* in_sizes, int n_in,
                              void* d_out, int out_size, void* d_ws, size_t ws_size,
                              hipStream_t stream){
  (void)in_sizes; (void)n_in; (void)out_size; (void)ws_size;
  const float* x      = (const float*)d_in[0];
  const float* ln1_g  = (const float*)d_in[1];
  const float* ln1_b  = (const float*)d_in[2];
  const float* qkv_w  = (const float*)d_in[3];
  const float* qkv_b  = (const float*)d_in[4];
  const float* proj_w = (const float*)d_in[5];
  const float* proj_b = (const float*)d_in[6];
  const float* ln2_g  = (const float*)d_in[7];
  const float* ln2_b  = (const float*)d_in[8];
  const float* fc1_w  = (const float*)d_in[9];
  const float* fc1_b  = (const float*)d_in[10];
  const float* fc2_w  = (const float*)d_in[11];
  const float* fc2_b  = (const float*)d_in[12];
  float* out = (float*)d_out;
  char* ws = (char*)d_ws;

  // workspace layout (bytes)
  unsigned short* ln_out  = (unsigned short*)(ws);                      // 25165824
  unsigned short* qkv_buf = (unsigned short*)(ws + 25165824);           // 75497472
  unsigned short* vTb     = (unsigned short*)(ws + 100663296);          // 25165824
  unsigned short* attn    = (unsigned short*)(ws + 125829120);          // 25165824
  unsigned short* hbuf    = qkv_buf;                                    // reuse (exactly 100663296)
  char* wbase = ws + 150994944;
  unsigned short* wq = (unsigned short*)(wbase);                        // 2304x768
  unsigned short* wp = (unsigned short*)(wbase + 3538944);              // 768x768
  unsigned short* w1 = (unsigned short*)(wbase + 4718592);              // 3072x768
  unsigned short* w2 = (unsigned short*)(wbase + 9437184);              // 768x3072

  wtrans<<<dim3(72, 24), 256, 0, stream>>>(qkv_w, wq, 768, 2304);
  wtrans<<<dim3(24, 24), 256, 0, stream>>>(proj_w, wp, 768, 768);
  wtrans<<<dim3(96, 24), 256, 0, stream>>>(fc1_w, w1, 768, 3072);
  wtrans<<<dim3(24, 96), 256, 0, stream>>>(fc2_w, w2, 3072, 768);

  ln_k<<<16384, 64, 0, stream>>>(x, ln1_g, ln1_b, ln_out);
  gemm_bt<0><<<128*18, 256, 0, stream>>>(ln_out, wq, qkv_b, nullptr, qkv_buf, 16384, 2304, 768);
  vextract<<<dim3(64, 192), 256, 0, stream>>>(qkv_buf, vTb);
  attn_k<<<dim3(8, 192), 256, 0, stream>>>(qkv_buf, vTb, attn);
  gemm_bt<1><<<128*6, 256, 0, stream>>>(attn, wp, proj_b, x, out, 16384, 768, 768);
  ln_k<<<16384, 64, 0, stream>>>(out, ln2_g, ln2_b, ln_out);
  gemm_bt<2><<<128*24, 256, 0, stream>>>(ln_out, w1, fc1_b, nullptr, hbuf, 16384, 3072, 768);
  gemm_bt<1><<<128*6, 256, 0, stream>>>(hbuf, w2, fc2_b, out, out, 16384, 768, 3072);
}